// Round 12
// baseline (542.265 us; speedup 1.0000x reference)
//
#include <hip/hip_runtime.h>
#include <math.h>

#define HW_ 16384

// ---------- module-global small scratch (f32, cross-kernel) ----------
#define WS_GE    0      // 1024: sum over H,W of |z| per (b,t,c)
#define WS_POOL  1024   // 4096: conv pooled partials [256 n*tile][16 co]
#define WS_DTEFF 5120   // 1024
#define WS_ROTRE 6144   // 1024
#define WS_ROTIM 7168   // 1024
#define WS_BV    8192   // 1024
#define WS_GB    9216   // 64
#define WS_NU    9280   // 1
__device__ float g_ws[10240];

// d_out (f32): [Re(u) S | Re(A) S | dt_eff 1024], S = 17,039,360.
// Scratch inside d_out (consumed before its region is written):
//   panel (row-FFT, 68.16 MB) at [S, 2S)         -- consumed by k_colfft2, overwritten by k_awrite
//   part  (conv partials, 67.1 MB) at [0, 16.8M) -- consumed by k_convf, overwritten by k_colfft2

// ---------- 128-point DIF FFT across one wave (2 complex elems / lane) ----------
struct Tw {
  float t0c, t0s;
  float c[6], s[6];
};

__device__ __forceinline__ void tw_init(int lane, Tw& tw) {
  sincospif(-(float)lane * (1.0f / 64.0f), &tw.t0s, &tw.t0c);
#pragma unroll
  for (int i = 0; i < 6; ++i) {
    int sp = 32 >> i;
    int j = lane & (sp - 1);
    float sv, cv;
    sincospif(-(float)j / (float)sp, &sv, &cv);
    bool bit = (lane & sp) != 0;
    tw.c[i] = bit ? cv : 1.0f;
    tw.s[i] = bit ? sv : 0.0f;
  }
}

__device__ __forceinline__ void fft128(int lane, float2& e0, float2& e1, const Tw& tw) {
  float ax = e0.x + e1.x, ay = e0.y + e1.y;
  float dx = e0.x - e1.x, dy = e0.y - e1.y;
  e0.x = ax; e0.y = ay;
  float t1x = dx * tw.t0c - dy * tw.t0s;
  float t1y = dx * tw.t0s + dy * tw.t0c;
  e1.x = t1x; e1.y = t1y;
#pragma unroll
  for (int i = 0; i < 6; ++i) {
    int sp = 32 >> i;
    bool bit = (lane & sp) != 0;
    float o0x = __shfl_xor(e0.x, sp, 64);
    float o0y = __shfl_xor(e0.y, sp, 64);
    float o1x = __shfl_xor(e1.x, sp, 64);
    float o1y = __shfl_xor(e1.y, sp, 64);
    float s0x = bit ? (o0x - e0.x) : (e0.x + o0x);
    float s0y = bit ? (o0y - e0.y) : (e0.y + o0y);
    float s1x = bit ? (o1x - e1.x) : (e1.x + o1x);
    float s1y = bit ? (o1y - e1.y) : (e1.y + o1y);
    e0.x = s0x * tw.c[i] - s0y * tw.s[i];
    e0.y = s0x * tw.s[i] + s0y * tw.c[i];
    e1.x = s1x * tw.c[i] - s1y * tw.s[i];
    e1.y = s1x * tw.s[i] + s1y * tw.c[i];
  }
}

// ---------- K1: row rFFTs of ONE real input (imag=0), f32 panel; optional |z| reduce ----------
__global__ __launch_bounds__(256) void k_rowfft2(
    const float* __restrict__ zsrc, const float* __restrict__ zother,
    float2* __restrict__ panel, int with_mag)
{
  __shared__ __align__(16) float2 Mr[65][34];
  __shared__ __align__(16) float2 Wb[4][128];
  __shared__ float redb[4];

  int n = blockIdx.x;                       // b*512 + t*64 + c
  int b = n >> 9, t = (n >> 6) & 7, c = n & 63;
  int tid = threadIdx.x, w = tid >> 6, lane = tid & 63;
  const float* pr = zsrc + (size_t)n * HW_;
  const float* po = zother + (size_t)n * HW_;
  Tw tw; tw_init(lane, tw);
  int k0 = (int)(__brev((unsigned)lane) >> 25);
  float msum = 0.0f;
  size_t base = ((size_t)((b * 8 + t) * 65)) * 8192 + (size_t)c * 128;

  for (int q = 0; q < 4; ++q) {
    for (int i = 0; i < 8; ++i) {
      int hl = w * 8 + i;
      int h = q * 32 + hl;
      float a0 = pr[h * 128 + lane];
      float a1 = pr[h * 128 + lane + 64];
      if (with_mag) {
        float b0 = po[h * 128 + lane];
        float b1 = po[h * 128 + lane + 64];
        msum += sqrtf(a0 * a0 + b0 * b0) + sqrtf(a1 * a1 + b1 * b1);
      }
      float2 e0 = make_float2(a0, 0.0f);
      float2 e1 = make_float2(a1, 0.0f);
      fft128(lane, e0, e1, tw);
      *(float4*)&Wb[w][k0] = make_float4(e0.x, e0.y, e1.x, e1.y);
      __syncthreads();
      Mr[lane][hl] = Wb[w][lane];
      if (lane == 0) Mr[64][hl] = Wb[w][64];
    }
    __syncthreads();
    for (int idx = tid; idx < 1040; idx += 256) {
      int f = idx * 2;
      int wf = f >> 5, hl = f & 31;
      float4 v = *(const float4*)&Mr[wf][hl];
      *(float4*)&panel[base + (size_t)wf * 8192 + q * 32 + hl] = v;
    }
    __syncthreads();
  }
  if (with_mag) {
#pragma unroll
    for (int off = 32; off; off >>= 1) msum += __shfl_down(msum, off, 64);
    if (lane == 0) redb[w] = msum;
    __syncthreads();
    if (tid == 0) g_ws[WS_GE + n] = redb[0] + redb[1] + redb[2] + redb[3];
  }
}

// ---------- K2a: conv partials over a 32-ci group (no bias/silu) ----------
// grid = 1024: bx = g*256 + n*16 + tile (g<4).
// R12: 8x32 thread map (4x1 px/thread) -> conflict-free xv; weights via
// wave-uniform GLOBAL reads (scalar K-cache loads) -> no weight LDS at all.
// part[bx*16384 + co*1024 + py*32 + px]
__global__ __launch_bounds__(256, 5) void k_convp(
    const float* __restrict__ zr, const float* __restrict__ zi,
    const float* __restrict__ conv_w, float* __restrict__ part)
{
  __shared__ float xs[34][35];

  int bx = blockIdx.x;
  int g = bx >> 8;
  int n = (bx >> 4) & 15;
  int tile = bx & 15;
  int ty0 = (tile >> 2) * 32, tx0 = (tile & 3) * 32;
  int tid = threadIdx.x;
  int ty = tid >> 5, tx = tid & 31;        // 8 x 32

  const float* zbase = (g < 2) ? zr : zi;
  int cbase = (g & 1) * 32;

  float acc[64];
#pragma unroll
  for (int i = 0; i < 64; ++i) acc[i] = 0.0f;

  for (int cil = 0; cil < 32; ++cil) {
    __syncthreads();                        // xs readers of previous iter done
    const float* plane = zbase + ((size_t)n * 64 + cbase + cil) * HW_;
    for (int i = tid; i < 1156; i += 256) {
      int r = i / 34;
      int col = i - r * 34;
      int gy = ty0 - 1 + r, gx = tx0 - 1 + col;
      float v = 0.0f;
      if (gy >= 0 && gy < 128 && gx >= 0 && gx < 128) v = plane[gy * 128 + gx];
      xs[r][col] = v;
    }
    __syncthreads();
    // 6x3 input window per thread (rows 4ty..4ty+5, cols tx..tx+2)
    float xv[18];
#pragma unroll
    for (int r2 = 0; r2 < 6; ++r2)
#pragma unroll
      for (int q = 0; q < 3; ++q)
        xv[r2 * 3 + q] = xs[4 * ty + r2][tx + q];
    // weights: wave-uniform address -> scalar loads, no LDS
    const float* wgrp = conv_w + (size_t)(g * 32 + cil) * 9;
#pragma unroll
    for (int co = 0; co < 16; ++co) {
      const float* wp = wgrp + (size_t)co * 1152;
      float w0 = wp[0], w1 = wp[1], w2 = wp[2], w3 = wp[3], w4 = wp[4];
      float w5 = wp[5], w6 = wp[6], w7 = wp[7], w8 = wp[8];
#pragma unroll
      for (int dy = 0; dy < 4; ++dy) {
        float s = xv[(dy + 0) * 3 + 0] * w0 + xv[(dy + 0) * 3 + 1] * w1 + xv[(dy + 0) * 3 + 2] * w2
                + xv[(dy + 1) * 3 + 0] * w3 + xv[(dy + 1) * 3 + 1] * w4 + xv[(dy + 1) * 3 + 2] * w5
                + xv[(dy + 2) * 3 + 0] * w6 + xv[(dy + 2) * 3 + 1] * w7 + xv[(dy + 2) * 3 + 2] * w8;
        acc[co * 4 + dy] += s;
      }
    }
  }
  // write partials: per (co,dy) 64 lanes cover rows {4ty, 4ty+dy} x tx 0..31 -> coalesced
  size_t pbase = (size_t)bx * 16384;
#pragma unroll
  for (int co = 0; co < 16; ++co)
#pragma unroll
    for (int dy = 0; dy < 4; ++dy)
      part[pbase + co * 1024 + (4 * ty + dy) * 32 + tx] = acc[co * 4 + dy];
}

// ---------- K2b: sum groups + bias + silu + spatial pool ----------
// grid = 4096: bx = (n*16+tile)*16 + co
__global__ __launch_bounds__(256) void k_convf(
    const float* __restrict__ part, const float* __restrict__ conv_b)
{
  __shared__ float red[256];
  int bx = blockIdx.x;
  int nt = bx >> 4, co = bx & 15;
  int tid = threadIdx.x;
  float cb = conv_b[co];
  float s = 0.0f;
#pragma unroll
  for (int k = 0; k < 4; ++k) {
    int px = tid + k * 256;
    float v = part[((size_t)(0 * 256 + nt)) * 16384 + co * 1024 + px]
            + part[((size_t)(1 * 256 + nt)) * 16384 + co * 1024 + px]
            + part[((size_t)(2 * 256 + nt)) * 16384 + co * 1024 + px]
            + part[((size_t)(3 * 256 + nt)) * 16384 + co * 1024 + px]
            + cb;
    s += v / (1.0f + expf(-v));
  }
  red[tid] = s;
  __syncthreads();
  for (int st = 128; st; st >>= 1) {
    if (tid < st) red[tid] += red[tid + st];
    __syncthreads();
  }
  if (tid == 0) g_ws[WS_POOL + nt * 16 + co] = red[0];
}

// ---------- K3: all small control math (single block) ----------
__global__ __launch_bounds__(256) void k_ctrl(
    const float* __restrict__ dtp, const float* __restrict__ lin_w, const float* __restrict__ lin_b,
    const float* __restrict__ sc_w1, const float* __restrict__ sc_b1,
    const float* __restrict__ sc_w2, const float* __restrict__ sc_b2,
    const float* __restrict__ L_gen, const float* __restrict__ diss_base, const float* __restrict__ visc,
    float* __restrict__ out_dteff)
{
  __shared__ float geL[16][64];
  __shared__ float poolL[16][16];
  __shared__ float alphaL[16];
  __shared__ float hid[16][32];
  __shared__ float ctl[16][128];
  int tid = threadIdx.x;
  for (int i = tid; i < 1024; i += 256) geL[i >> 6][i & 63] = g_ws[WS_GE + i] * (1.0f / 16384.0f);
  {
    int nn = tid >> 4, co = tid & 15;
    float s = 0.0f;
    for (int tile = 0; tile < 16; ++tile) s += g_ws[WS_POOL + (nn * 16 + tile) * 16 + co];
    poolL[nn][co] = s * (1.0f / 16384.0f);
  }
  __syncthreads();
  if (tid < 16) {
    float s = lin_b[0];
    for (int co = 0; co < 16; ++co) s += poolL[tid][co] * lin_w[co];
    alphaL[tid] = 1.0f / (1.0f + expf(-s));
  }
  for (int i = tid; i < 512; i += 256) {
    int nn = i >> 5, j = i & 31;
    float s = sc_b1[j];
    for (int cc = 0; cc < 64; ++cc) s += geL[nn][cc] * sc_w1[j * 64 + cc];
    hid[nn][j] = s / (1.0f + expf(-s));
  }
  __syncthreads();
  for (int i = tid; i < 2048; i += 256) {
    int nn = i >> 7, kk = i & 127;
    int k = (kk < 64) ? kk : (kk + 64);
    float s = sc_b2[k];
    for (int j = 0; j < 32; ++j) s += hid[nn][j] * sc_w2[k * 32 + j];
    ctl[nn][kk] = tanhf(s);
  }
  __syncthreads();
  float dtv = dtp[0];
  for (int e = tid; e < 1024; e += 256) {
    int nn = e >> 6, cc = e & 63;
    float gem = geL[nn][cc];
    float dtmax = 1.0f / (10.0f * (gem + 1e-6f));
    float dte = alphaL[nn] * fminf(dtv, dtmax);
    float om = L_gen[cc] + 0.1f * ctl[nn][cc];
    float x = 0.5f * om * dte;
    float inv = 1.0f / (1.0f + x * x);
    g_ws[WS_DTEFF + e] = dte;
    g_ws[WS_ROTRE + e] = (1.0f - x * x) * inv;
    g_ws[WS_ROTIM + e] = 2.0f * x * inv;
    float vv = ctl[nn][64 + cc];
    g_ws[WS_BV + e] = 2.0f / (1.0f + expf(-vv));
    out_dteff[e] = dte;
  }
  if (tid < 64) g_ws[WS_GB + tid] = -log1pf(expf(diss_base[tid]));
  if (tid == 0) g_ws[WS_NU] = log1pf(expf(visc[0]));
}

// ---------- K4: column FFTs + Bv/128 scale + REAL-PART f32 u-write ----------
__global__ __launch_bounds__(256) void k_colfft2(
    const float2* __restrict__ panel, float* __restrict__ outU, int ubbase)
{
  __shared__ __align__(16) float2 M2[32][132];
  __shared__ float fs[64];
  int bx = blockIdx.x;                      // b*520 + t*65 + wf
  int b = bx / 520;
  int rem = bx - b * 520;
  int t = rem / 65;
  int wf = rem - t * 65;
  int ub = ubbase + b;
  int tid = threadIdx.x, w = tid >> 6, lane = tid & 63;
  Tw tw; tw_init(lane, tw);
  int k0 = (int)(__brev((unsigned)lane) >> 25);
  const float2* src = panel + (((size_t)(b * 8 + t)) * 65 + wf) * 8192;
  if (tid < 64) fs[tid] = g_ws[WS_BV + b * 512 + t * 64 + tid] * (1.0f / 128.0f);
  size_t ob = ((((size_t)ub * 128) * 65 + (size_t)wf) * 8 + (size_t)t) * 64;
  for (int q = 0; q < 2; ++q) {
    __syncthreads();
    for (int i = tid; i < 2048; i += 256) {
      float4 v = *(const float4*)&src[(size_t)q * 4096 + (size_t)i * 2];
      int f = i * 2;
      int cl = f >> 7, hh = f & 127;
      *(float4*)&M2[cl][hh] = v;
    }
    __syncthreads();
    for (int i = 0; i < 8; ++i) {
      int cl = w * 8 + i;
      float2 e0 = M2[cl][lane];
      float2 e1 = M2[cl][lane + 64];
      fft128(lane, e0, e1, tw);
      *(float4*)&M2[cl][k0] = make_float4(e0.x, e0.y, e1.x, e1.y);
    }
    __syncthreads();
    for (int idx = tid; idx < 2048; idx += 256) {
      int h = idx >> 4, cl2 = (idx & 15) * 2;
      int cc = q * 32 + cl2;
      float re0 = M2[cl2][h].x;
      float re1 = M2[cl2 + 1][h].x;
      float2 o = make_float2(re0 * fs[cc], re1 * fs[cc + 1]);
      *(float2*)&outU[ob + (size_t)h * 33280 + cc] = o;
    }
  }
}

// ---------- K5: A writer, REAL PART f32 at [S, 2S) ----------
__global__ __launch_bounds__(256) void k_awrite(float* __restrict__ outA)
{
  int bx = blockIdx.x;
  int h = bx / 65;
  int wf = bx - h * 65;
  float kxv = (float)wf * (1.0f / 128.0f);
  float kyf = (h < 64) ? (float)h : (float)(h - 128);
  float kyv = kyf * (1.0f / 128.0f);
  float ksq = kxv * kxv + kyv * kyv;
  float nu = g_ws[WS_NU];
  int tid = threadIdx.x;
  for (int e2 = tid; e2 < 512; e2 += 256) {
    int b = e2 >> 8, t = (e2 >> 5) & 7, cc = (e2 & 31) * 2;
    int e = b * 512 + t * 64 + cc;
    float gk0 = g_ws[WS_GB + cc] - nu * ksq;
    float gk1 = g_ws[WS_GB + cc + 1] - nu * ksq;
    float ad0 = expf(gk0 * g_ws[WS_DTEFF + e]);
    float ad1 = expf(gk1 * g_ws[WS_DTEFF + e + 1]);
    float2 vre = make_float2(ad0 * g_ws[WS_ROTRE + e], ad1 * g_ws[WS_ROTRE + e + 1]);
    size_t o1 = ((((size_t)(b * 128 + h)) * 65 + wf) * 8 + t) * 64 + cc;
    size_t o2 = o1 + 8519680ull;
    *(float2*)&outA[o1] = vre;
    *(float2*)&outA[o2] = vre;
  }
}

extern "C" void kernel_launch(void* const* d_in, const int* in_sizes, int n_in,
                              void* d_out, int out_size, void* d_ws, size_t ws_size,
                              hipStream_t stream)
{
  (void)in_sizes; (void)n_in; (void)d_ws; (void)ws_size;
  const float* zr     = (const float*)d_in[0];
  const float* zi     = (const float*)d_in[1];
  const float* dtp    = (const float*)d_in[2];
  const float* conv_w = (const float*)d_in[3];
  const float* conv_b = (const float*)d_in[4];
  const float* lin_w  = (const float*)d_in[5];
  const float* lin_b  = (const float*)d_in[6];
  const float* sc_w1  = (const float*)d_in[7];
  const float* sc_b1  = (const float*)d_in[8];
  const float* sc_w2  = (const float*)d_in[9];
  const float* sc_b2  = (const float*)d_in[10];
  const float* L_gen  = (const float*)d_in[11];
  const float* diss   = (const float*)d_in[12];
  const float* visc   = (const float*)d_in[13];

  float* out = (float*)d_out;
  size_t S = ((size_t)out_size - 1024) / 2;     // 17,039,360
  float* dt_out = out + (size_t)out_size - 1024;
  float2* panel = (float2*)(out + S);           // row-FFT panel in A-region
  float* part = out;                            // conv partials in u-region (16.8M < S)

  k_rowfft2<<<1024, 256, 0, stream>>>(zr, zi, panel, 1);   // z_real rows + |z| reduce
  k_convp  <<<1024, 256, 0, stream>>>(zr, zi, conv_w, part);
  k_convf  <<<4096, 256, 0, stream>>>(part, conv_b);
  k_ctrl   <<<1, 256, 0, stream>>>(dtp, lin_w, lin_b, sc_w1, sc_b1, sc_w2, sc_b2, L_gen, diss, visc, dt_out);
  k_colfft2<<<1040, 256, 0, stream>>>(panel, out, 0);      // Re(u) for ub = 0,1 (overwrites part)
  k_rowfft2<<<1024, 256, 0, stream>>>(zi, zi, panel, 0);   // z_imag rows
  k_colfft2<<<1040, 256, 0, stream>>>(panel, out, 2);      // Re(u) for ub = 2,3
  k_awrite <<<8320, 256, 0, stream>>>(out + S);
}

// Round 13
// 513.127 us; speedup vs baseline: 1.0568x; 1.0568x over previous
//
#include <hip/hip_runtime.h>
#include <math.h>

#define HW_ 16384

// ---------- module-global small scratch (f32, cross-kernel) ----------
#define WS_GE    0      // 1024: sum over H,W of |z| per (b,t,c)
#define WS_POOL  1024   // 16384: conv pooled partials [1024 blocks][16 co]
#define WS_DTEFF 17408  // 1024
#define WS_ROTRE 18432  // 1024
#define WS_ROTIM 19456  // 1024
#define WS_BV    20480  // 1024
#define WS_GB    21504  // 64
#define WS_NU    21568  // 1
__device__ float g_ws[22528];

// d_out (f32): [Re(u) S | Re(A) S | dt_eff 1024], S = 17,039,360.
// panel (row-FFT, 68.16 MB) lives at [S, 2S); consumed by k_colfft2 before
// k_awrite overwrites it.

// ---------- 128-point DIF FFT across one wave (2 complex elems / lane) ----------
struct Tw {
  float t0c, t0s;
  float c[6], s[6];
};

__device__ __forceinline__ void tw_init(int lane, Tw& tw) {
  sincospif(-(float)lane * (1.0f / 64.0f), &tw.t0s, &tw.t0c);
#pragma unroll
  for (int i = 0; i < 6; ++i) {
    int sp = 32 >> i;
    int j = lane & (sp - 1);
    float sv, cv;
    sincospif(-(float)j / (float)sp, &sv, &cv);
    bool bit = (lane & sp) != 0;
    tw.c[i] = bit ? cv : 1.0f;
    tw.s[i] = bit ? sv : 0.0f;
  }
}

__device__ __forceinline__ void fft128(int lane, float2& e0, float2& e1, const Tw& tw) {
  float ax = e0.x + e1.x, ay = e0.y + e1.y;
  float dx = e0.x - e1.x, dy = e0.y - e1.y;
  e0.x = ax; e0.y = ay;
  float t1x = dx * tw.t0c - dy * tw.t0s;
  float t1y = dx * tw.t0s + dy * tw.t0c;
  e1.x = t1x; e1.y = t1y;
#pragma unroll
  for (int i = 0; i < 6; ++i) {
    int sp = 32 >> i;
    bool bit = (lane & sp) != 0;
    float o0x = __shfl_xor(e0.x, sp, 64);
    float o0y = __shfl_xor(e0.y, sp, 64);
    float o1x = __shfl_xor(e1.x, sp, 64);
    float o1y = __shfl_xor(e1.y, sp, 64);
    float s0x = bit ? (o0x - e0.x) : (e0.x + o0x);
    float s0y = bit ? (o0y - e0.y) : (e0.y + o0y);
    float s1x = bit ? (o1x - e1.x) : (e1.x + o1x);
    float s1y = bit ? (o1y - e1.y) : (e1.y + o1y);
    e0.x = s0x * tw.c[i] - s0y * tw.s[i];
    e0.y = s0x * tw.s[i] + s0y * tw.c[i];
    e1.x = s1x * tw.c[i] - s1y * tw.s[i];
    e1.y = s1x * tw.s[i] + s1y * tw.c[i];
  }
}

// ---------- K1: row rFFTs of ONE real input (imag=0), f32 panel; optional |z| reduce ----------
__global__ __launch_bounds__(256) void k_rowfft2(
    const float* __restrict__ zsrc, const float* __restrict__ zother,
    float2* __restrict__ panel, int with_mag)
{
  __shared__ __align__(16) float2 Mr[65][34];
  __shared__ __align__(16) float2 Wb[4][128];
  __shared__ float redb[4];

  int n = blockIdx.x;                       // b*512 + t*64 + c
  int b = n >> 9, t = (n >> 6) & 7, c = n & 63;
  int tid = threadIdx.x, w = tid >> 6, lane = tid & 63;
  const float* pr = zsrc + (size_t)n * HW_;
  const float* po = zother + (size_t)n * HW_;
  Tw tw; tw_init(lane, tw);
  int k0 = (int)(__brev((unsigned)lane) >> 25);
  float msum = 0.0f;
  size_t base = ((size_t)((b * 8 + t) * 65)) * 8192 + (size_t)c * 128;

  for (int q = 0; q < 4; ++q) {
    for (int i = 0; i < 8; ++i) {
      int hl = w * 8 + i;
      int h = q * 32 + hl;
      float a0 = pr[h * 128 + lane];
      float a1 = pr[h * 128 + lane + 64];
      if (with_mag) {
        float b0 = po[h * 128 + lane];
        float b1 = po[h * 128 + lane + 64];
        msum += sqrtf(a0 * a0 + b0 * b0) + sqrtf(a1 * a1 + b1 * b1);
      }
      float2 e0 = make_float2(a0, 0.0f);
      float2 e1 = make_float2(a1, 0.0f);
      fft128(lane, e0, e1, tw);
      *(float4*)&Wb[w][k0] = make_float4(e0.x, e0.y, e1.x, e1.y);
      __syncthreads();
      Mr[lane][hl] = Wb[w][lane];
      if (lane == 0) Mr[64][hl] = Wb[w][64];
    }
    __syncthreads();
    for (int idx = tid; idx < 1040; idx += 256) {
      int f = idx * 2;
      int wf = f >> 5, hl = f & 31;
      float4 v = *(const float4*)&Mr[wf][hl];
      *(float4*)&panel[base + (size_t)wf * 8192 + q * 32 + hl] = v;
    }
    __syncthreads();
  }
  if (with_mag) {
#pragma unroll
    for (int off = 32; off; off >>= 1) msum += __shfl_down(msum, off, 64);
    if (lane == 0) redb[w] = msum;
    __syncthreads();
    if (tid == 0) g_ws[WS_GE + n] = redb[0] + redb[1] + redb[2] + redb[3];
  }
}

// ---------- K2: fused conv(128->16) + silu + pool, 1 px/thread ----------
// grid = 1024: bx = n*64 + tsub; tsub = ry*8 + cx; tile 16x16.
// acc[16] only -> ~40 VGPR, no spill; 8 blocks/CU -> 8 waves/SIMD.
// Weights via wave-uniform scalar loads (K-cache).
__global__ __launch_bounds__(256) void k_conv1(
    const float* __restrict__ zr, const float* __restrict__ zi,
    const float* __restrict__ conv_w, const float* __restrict__ conv_b)
{
  __shared__ float xs[18][24];   // stride 24: lane footprint is exactly 2-way/bank (free)
  __shared__ float redb[4][16];

  int bx = blockIdx.x;
  int n = bx >> 6, tsub = bx & 63;
  int ty0 = (tsub >> 3) * 16, tx0 = (tsub & 7) * 16;
  int tid = threadIdx.x;
  int py = tid >> 4, px = tid & 15;   // 16 x 16

  float acc[16];
#pragma unroll
  for (int i = 0; i < 16; ++i) acc[i] = 0.0f;

  for (int ci = 0; ci < 128; ++ci) {
    __syncthreads();                  // xs readers of previous iter done
    const float* plane = ((ci < 64) ? zr : zi) + ((size_t)n * 64 + (ci & 63)) * HW_;
    for (int i = tid; i < 324; i += 256) {   // 18 x 18 halo
      int r = i / 18, col = i - r * 18;
      int gy = ty0 - 1 + r, gx = tx0 - 1 + col;
      float v = 0.0f;
      if (gy >= 0 && gy < 128 && gx >= 0 && gx < 128) v = plane[gy * 128 + gx];
      xs[r][col] = v;
    }
    __syncthreads();
    float x0 = xs[py][px],     x1 = xs[py][px + 1],     x2 = xs[py][px + 2];
    float x3 = xs[py + 1][px], x4 = xs[py + 1][px + 1], x5 = xs[py + 1][px + 2];
    float x6 = xs[py + 2][px], x7 = xs[py + 2][px + 1], x8 = xs[py + 2][px + 2];
    const float* wci = conv_w + (size_t)ci * 9;      // wave-uniform
#pragma unroll
    for (int co = 0; co < 16; ++co) {
      const float* wp = wci + (size_t)co * 1152;
      acc[co] += x0 * wp[0] + x1 * wp[1] + x2 * wp[2]
               + x3 * wp[3] + x4 * wp[4] + x5 * wp[5]
               + x6 * wp[6] + x7 * wp[7] + x8 * wp[8];
    }
  }
  // bias + silu + pool over this 16x16 tile
  int w = tid >> 6, lane = tid & 63;
#pragma unroll
  for (int co = 0; co < 16; ++co) {
    float v = acc[co] + conv_b[co];
    v = v / (1.0f + expf(-v));
#pragma unroll
    for (int off = 32; off; off >>= 1) v += __shfl_down(v, off, 64);
    if (lane == 0) redb[w][co] = v;
  }
  __syncthreads();
  if (tid < 16) {
    g_ws[WS_POOL + bx * 16 + tid] = redb[0][tid] + redb[1][tid] + redb[2][tid] + redb[3][tid];
  }
}

// ---------- K3: all small control math (single block) ----------
__global__ __launch_bounds__(256) void k_ctrl(
    const float* __restrict__ dtp, const float* __restrict__ lin_w, const float* __restrict__ lin_b,
    const float* __restrict__ sc_w1, const float* __restrict__ sc_b1,
    const float* __restrict__ sc_w2, const float* __restrict__ sc_b2,
    const float* __restrict__ L_gen, const float* __restrict__ diss_base, const float* __restrict__ visc,
    float* __restrict__ out_dteff)
{
  __shared__ float geL[16][64];
  __shared__ float poolL[16][16];
  __shared__ float alphaL[16];
  __shared__ float hid[16][32];
  __shared__ float ctl[16][128];
  int tid = threadIdx.x;
  for (int i = tid; i < 1024; i += 256) geL[i >> 6][i & 63] = g_ws[WS_GE + i] * (1.0f / 16384.0f);
  {
    int nn = tid >> 4, co = tid & 15;
    float s = 0.0f;
    for (int tile = 0; tile < 64; ++tile) s += g_ws[WS_POOL + (nn * 64 + tile) * 16 + co];
    poolL[nn][co] = s * (1.0f / 16384.0f);
  }
  __syncthreads();
  if (tid < 16) {
    float s = lin_b[0];
    for (int co = 0; co < 16; ++co) s += poolL[tid][co] * lin_w[co];
    alphaL[tid] = 1.0f / (1.0f + expf(-s));
  }
  for (int i = tid; i < 512; i += 256) {
    int nn = i >> 5, j = i & 31;
    float s = sc_b1[j];
    for (int cc = 0; cc < 64; ++cc) s += geL[nn][cc] * sc_w1[j * 64 + cc];
    hid[nn][j] = s / (1.0f + expf(-s));
  }
  __syncthreads();
  for (int i = tid; i < 2048; i += 256) {
    int nn = i >> 7, kk = i & 127;
    int k = (kk < 64) ? kk : (kk + 64);
    float s = sc_b2[k];
    for (int j = 0; j < 32; ++j) s += hid[nn][j] * sc_w2[k * 32 + j];
    ctl[nn][kk] = tanhf(s);
  }
  __syncthreads();
  float dtv = dtp[0];
  for (int e = tid; e < 1024; e += 256) {
    int nn = e >> 6, cc = e & 63;
    float gem = geL[nn][cc];
    float dtmax = 1.0f / (10.0f * (gem + 1e-6f));
    float dte = alphaL[nn] * fminf(dtv, dtmax);
    float om = L_gen[cc] + 0.1f * ctl[nn][cc];
    float x = 0.5f * om * dte;
    float inv = 1.0f / (1.0f + x * x);
    g_ws[WS_DTEFF + e] = dte;
    g_ws[WS_ROTRE + e] = (1.0f - x * x) * inv;
    g_ws[WS_ROTIM + e] = 2.0f * x * inv;
    float vv = ctl[nn][64 + cc];
    g_ws[WS_BV + e] = 2.0f / (1.0f + expf(-vv));
    out_dteff[e] = dte;
  }
  if (tid < 64) g_ws[WS_GB + tid] = -log1pf(expf(diss_base[tid]));
  if (tid == 0) g_ws[WS_NU] = log1pf(expf(visc[0]));
}

// ---------- K4: column FFTs + Bv/128 scale + REAL-PART f32 u-write ----------
__global__ __launch_bounds__(256) void k_colfft2(
    const float2* __restrict__ panel, float* __restrict__ outU, int ubbase)
{
  __shared__ __align__(16) float2 M2[32][132];
  __shared__ float fs[64];
  int bx = blockIdx.x;                      // b*520 + t*65 + wf
  int b = bx / 520;
  int rem = bx - b * 520;
  int t = rem / 65;
  int wf = rem - t * 65;
  int ub = ubbase + b;
  int tid = threadIdx.x, w = tid >> 6, lane = tid & 63;
  Tw tw; tw_init(lane, tw);
  int k0 = (int)(__brev((unsigned)lane) >> 25);
  const float2* src = panel + (((size_t)(b * 8 + t)) * 65 + wf) * 8192;
  if (tid < 64) fs[tid] = g_ws[WS_BV + b * 512 + t * 64 + tid] * (1.0f / 128.0f);
  size_t ob = ((((size_t)ub * 128) * 65 + (size_t)wf) * 8 + (size_t)t) * 64;
  for (int q = 0; q < 2; ++q) {
    __syncthreads();
    for (int i = tid; i < 2048; i += 256) {
      float4 v = *(const float4*)&src[(size_t)q * 4096 + (size_t)i * 2];
      int f = i * 2;
      int cl = f >> 7, hh = f & 127;
      *(float4*)&M2[cl][hh] = v;
    }
    __syncthreads();
    for (int i = 0; i < 8; ++i) {
      int cl = w * 8 + i;
      float2 e0 = M2[cl][lane];
      float2 e1 = M2[cl][lane + 64];
      fft128(lane, e0, e1, tw);
      *(float4*)&M2[cl][k0] = make_float4(e0.x, e0.y, e1.x, e1.y);
    }
    __syncthreads();
    for (int idx = tid; idx < 2048; idx += 256) {
      int h = idx >> 4, cl2 = (idx & 15) * 2;
      int cc = q * 32 + cl2;
      float re0 = M2[cl2][h].x;
      float re1 = M2[cl2 + 1][h].x;
      float2 o = make_float2(re0 * fs[cc], re1 * fs[cc + 1]);
      *(float2*)&outU[ob + (size_t)h * 33280 + cc] = o;
    }
  }
}

// ---------- K5: A writer, REAL PART f32 at [S, 2S) ----------
__global__ __launch_bounds__(256) void k_awrite(float* __restrict__ outA)
{
  int bx = blockIdx.x;
  int h = bx / 65;
  int wf = bx - h * 65;
  float kxv = (float)wf * (1.0f / 128.0f);
  float kyf = (h < 64) ? (float)h : (float)(h - 128);
  float kyv = kyf * (1.0f / 128.0f);
  float ksq = kxv * kxv + kyv * kyv;
  float nu = g_ws[WS_NU];
  int tid = threadIdx.x;
  for (int e2 = tid; e2 < 512; e2 += 256) {
    int b = e2 >> 8, t = (e2 >> 5) & 7, cc = (e2 & 31) * 2;
    int e = b * 512 + t * 64 + cc;
    float gk0 = g_ws[WS_GB + cc] - nu * ksq;
    float gk1 = g_ws[WS_GB + cc + 1] - nu * ksq;
    float ad0 = expf(gk0 * g_ws[WS_DTEFF + e]);
    float ad1 = expf(gk1 * g_ws[WS_DTEFF + e + 1]);
    float2 vre = make_float2(ad0 * g_ws[WS_ROTRE + e], ad1 * g_ws[WS_ROTRE + e + 1]);
    size_t o1 = ((((size_t)(b * 128 + h)) * 65 + wf) * 8 + t) * 64 + cc;
    size_t o2 = o1 + 8519680ull;
    *(float2*)&outA[o1] = vre;
    *(float2*)&outA[o2] = vre;
  }
}

extern "C" void kernel_launch(void* const* d_in, const int* in_sizes, int n_in,
                              void* d_out, int out_size, void* d_ws, size_t ws_size,
                              hipStream_t stream)
{
  (void)in_sizes; (void)n_in; (void)d_ws; (void)ws_size;
  const float* zr     = (const float*)d_in[0];
  const float* zi     = (const float*)d_in[1];
  const float* dtp    = (const float*)d_in[2];
  const float* conv_w = (const float*)d_in[3];
  const float* conv_b = (const float*)d_in[4];
  const float* lin_w  = (const float*)d_in[5];
  const float* lin_b  = (const float*)d_in[6];
  const float* sc_w1  = (const float*)d_in[7];
  const float* sc_b1  = (const float*)d_in[8];
  const float* sc_w2  = (const float*)d_in[9];
  const float* sc_b2  = (const float*)d_in[10];
  const float* L_gen  = (const float*)d_in[11];
  const float* diss   = (const float*)d_in[12];
  const float* visc   = (const float*)d_in[13];

  float* out = (float*)d_out;
  size_t S = ((size_t)out_size - 1024) / 2;     // 17,039,360
  float* dt_out = out + (size_t)out_size - 1024;
  float2* panel = (float2*)(out + S);           // row-FFT panel in A-region

  k_rowfft2<<<1024, 256, 0, stream>>>(zr, zi, panel, 1);   // z_real rows + |z| reduce
  k_conv1  <<<1024, 256, 0, stream>>>(zr, zi, conv_w, conv_b);
  k_ctrl   <<<1, 256, 0, stream>>>(dtp, lin_w, lin_b, sc_w1, sc_b1, sc_w2, sc_b2, L_gen, diss, visc, dt_out);
  k_colfft2<<<1040, 256, 0, stream>>>(panel, out, 0);      // Re(u) for ub = 0,1
  k_rowfft2<<<1024, 256, 0, stream>>>(zi, zi, panel, 0);   // z_imag rows
  k_colfft2<<<1040, 256, 0, stream>>>(panel, out, 2);      // Re(u) for ub = 2,3
  k_awrite <<<8320, 256, 0, stream>>>(out + S);
}

// Round 14
// 427.385 us; speedup vs baseline: 1.2688x; 1.2006x over previous
//
#include <hip/hip_runtime.h>
#include <math.h>

#define HW_ 16384

// ---------- module-global small scratch (f32, cross-kernel) ----------
#define WS_GE    0      // 1024
#define WS_POOL  1024   // 16384: [1024 blocks][16 co]
#define WS_DTEFF 17408  // 1024
#define WS_ROTRE 18432  // 1024
#define WS_ROTIM 19456  // 1024
#define WS_BV    20480  // 1024
#define WS_GB    21504  // 64
#define WS_NU    21568  // 1
__device__ float g_ws[22528];

// d_out (f32): [Re(u) S | Re(A) S | dt_eff 1024], S = 17,039,360.
// A-region holds TWO bf16 row-FFT panels (panelR | panelI), 34 MB each = 68 MB
// exactly; consumed by k_colfft2 before k_awrite overwrites.

__device__ __forceinline__ unsigned short f2bf(float f) {
  unsigned u = __float_as_uint(f);
  u += 0x7fffu + ((u >> 16) & 1u);
  return (unsigned short)(u >> 16);
}
__device__ __forceinline__ float bf2f(unsigned short h) {
  return __uint_as_float((unsigned)h << 16);
}

// ---------- 128-point DIF FFT across one wave (2 complex elems / lane) ----------
struct Tw {
  float t0c, t0s;
  float c[6], s[6];
};

__device__ __forceinline__ void tw_init(int lane, Tw& tw) {
  sincospif(-(float)lane * (1.0f / 64.0f), &tw.t0s, &tw.t0c);
#pragma unroll
  for (int i = 0; i < 6; ++i) {
    int sp = 32 >> i;
    int j = lane & (sp - 1);
    float sv, cv;
    sincospif(-(float)j / (float)sp, &sv, &cv);
    bool bit = (lane & sp) != 0;
    tw.c[i] = bit ? cv : 1.0f;
    tw.s[i] = bit ? sv : 0.0f;
  }
}

__device__ __forceinline__ void fft128(int lane, float2& e0, float2& e1, const Tw& tw) {
  float ax = e0.x + e1.x, ay = e0.y + e1.y;
  float dx = e0.x - e1.x, dy = e0.y - e1.y;
  e0.x = ax; e0.y = ay;
  float t1x = dx * tw.t0c - dy * tw.t0s;
  float t1y = dx * tw.t0s + dy * tw.t0c;
  e1.x = t1x; e1.y = t1y;
#pragma unroll
  for (int i = 0; i < 6; ++i) {
    int sp = 32 >> i;
    bool bit = (lane & sp) != 0;
    float o0x = __shfl_xor(e0.x, sp, 64);
    float o0y = __shfl_xor(e0.y, sp, 64);
    float o1x = __shfl_xor(e1.x, sp, 64);
    float o1y = __shfl_xor(e1.y, sp, 64);
    float s0x = bit ? (o0x - e0.x) : (e0.x + o0x);
    float s0y = bit ? (o0y - e0.y) : (e0.y + o0y);
    float s1x = bit ? (o1x - e1.x) : (e1.x + o1x);
    float s1y = bit ? (o1y - e1.y) : (e1.y + o1y);
    e0.x = s0x * tw.c[i] - s0y * tw.s[i];
    e0.y = s0x * tw.s[i] + s0y * tw.c[i];
    e1.x = s1x * tw.c[i] - s1y * tw.s[i];
    e1.y = s1x * tw.s[i] + s1y * tw.c[i];
  }
}

// ---------- K1: packed row rFFTs (zr + i*zi) -> TWO bf16 panels + |z| reduce ----------
// Unpack identities bit-proven in R3 (== oracle DFT after bf16).
__global__ __launch_bounds__(256) void k_rowfftP(
    const float* __restrict__ zr, const float* __restrict__ zi,
    ushort2* __restrict__ panelR, ushort2* __restrict__ panelI)
{
  __shared__ __align__(16) float2 Mr[65][34];
  __shared__ __align__(16) float2 Mi[65][34];
  __shared__ __align__(16) float2 Wb[4][128];
  __shared__ float redb[4];

  int n = blockIdx.x;                       // b*512 + t*64 + c
  int b = n >> 9, t = (n >> 6) & 7, c = n & 63;
  int tid = threadIdx.x, w = tid >> 6, lane = tid & 63;
  const float* pr = zr + (size_t)n * HW_;
  const float* pim = zi + (size_t)n * HW_;
  Tw tw; tw_init(lane, tw);
  int k0 = (int)(__brev((unsigned)lane) >> 25);
  float msum = 0.0f;
  size_t base = ((size_t)((b * 8 + t) * 65)) * 8192 + (size_t)c * 128;

  for (int q = 0; q < 4; ++q) {
    for (int i = 0; i < 8; ++i) {
      int hl = w * 8 + i;
      int h = q * 32 + hl;
      float a0 = pr[h * 128 + lane];
      float a1 = pr[h * 128 + lane + 64];
      float b0 = pim[h * 128 + lane];
      float b1 = pim[h * 128 + lane + 64];
      msum += sqrtf(a0 * a0 + b0 * b0) + sqrtf(a1 * a1 + b1 * b1);
      float2 e0 = make_float2(a0, b0);      // packed: zr + i*zi
      float2 e1 = make_float2(a1, b1);
      fft128(lane, e0, e1, tw);
      *(float4*)&Wb[w][k0] = make_float4(e0.x, e0.y, e1.x, e1.y);
      __syncthreads();
      float2 Zk = Wb[w][lane];
      float2 Zm = Wb[w][(128 - lane) & 127];
      Mr[lane][hl] = make_float2(0.5f * (Zk.x + Zm.x), 0.5f * (Zk.y - Zm.y));
      Mi[lane][hl] = make_float2(0.5f * (Zk.y + Zm.y), 0.5f * (Zm.x - Zk.x));
      if (lane == 0) {
        float2 Z64 = Wb[w][64];
        Mr[64][hl] = make_float2(Z64.x, 0.0f);
        Mi[64][hl] = make_float2(Z64.y, 0.0f);
      }
    }
    __syncthreads();
    for (int idx = tid; idx < 1040; idx += 256) {   // 65*32/2 two-complex units
      int f = idx * 2;
      int wf = f >> 5, hl = f & 31;
      float4 vr = *(const float4*)&Mr[wf][hl];
      float4 vi = *(const float4*)&Mi[wf][hl];
      ushort4 ur = make_ushort4(f2bf(vr.x), f2bf(vr.y), f2bf(vr.z), f2bf(vr.w));
      ushort4 ui = make_ushort4(f2bf(vi.x), f2bf(vi.y), f2bf(vi.z), f2bf(vi.w));
      *(ushort4*)&panelR[base + (size_t)wf * 8192 + q * 32 + hl] = ur;
      *(ushort4*)&panelI[base + (size_t)wf * 8192 + q * 32 + hl] = ui;
    }
    __syncthreads();
  }
#pragma unroll
  for (int off = 32; off; off >>= 1) msum += __shfl_down(msum, off, 64);
  if (lane == 0) redb[w] = msum;
  __syncthreads();
  if (tid == 0) g_ws[WS_GE + n] = redb[0] + redb[1] + redb[2] + redb[3];
}

// ---------- K2: fused conv(128->16) + silu + pool; named accs, T14 prefetch ----------
__global__ __launch_bounds__(256, 4) void k_conv1(
    const float* __restrict__ zr, const float* __restrict__ zi,
    const float* __restrict__ conv_w, const float* __restrict__ conv_b)
{
  __shared__ float xs[18][24];
  __shared__ float redb[4][16];

  int bx = blockIdx.x;
  int n = bx >> 6, tsub = bx & 63;
  int ty0 = (tsub >> 3) * 16, tx0 = (tsub & 7) * 16;
  int tid = threadIdx.x;
  int py = tid >> 4, px = tid & 15;

  int r0 = tid / 18, c0 = tid - r0 * 18;
  int gy0 = ty0 - 1 + r0, gx0 = tx0 - 1 + c0;
  bool ok0 = (gy0 >= 0) && (gy0 < 128) && (gx0 >= 0) && (gx0 < 128);
  int i1 = tid + 256;
  int r1 = i1 / 18, c1 = i1 - r1 * 18;
  int gy1 = ty0 - 1 + r1, gx1 = tx0 - 1 + c1;
  bool has1 = (i1 < 324);
  bool ok1 = has1 && (gy1 >= 0) && (gy1 < 128) && (gx1 >= 0) && (gx1 < 128);
  int off0 = gy0 * 128 + gx0;
  int off1 = gy1 * 128 + gx1;

  const float* pbr = zr + (size_t)n * 64 * HW_;
  const float* pbi = zi + (size_t)n * 64 * HW_;

  float acc0=0,acc1=0,acc2=0,acc3=0,acc4=0,acc5=0,acc6=0,acc7=0;
  float acc8=0,acc9=0,acc10=0,acc11=0,acc12=0,acc13=0,acc14=0,acc15=0;

  // prefetch ci = 0
  float nxt0 = ok0 ? pbr[off0] : 0.0f;
  float nxt1 = ok1 ? pbr[off1] : 0.0f;

  for (int ci = 0; ci < 128; ++ci) {
    __syncthreads();                 // previous iter's xs readers done
    xs[r0][c0] = nxt0;
    if (has1) xs[r1][c1] = nxt1;
    __syncthreads();
    if (ci + 1 < 128) {              // T14: issue next plane's loads, hide under FMAs
      const float* pl = ((ci + 1) < 64 ? pbr : pbi) + (size_t)((ci + 1) & 63) * HW_;
      nxt0 = ok0 ? pl[off0] : 0.0f;
      nxt1 = ok1 ? pl[off1] : 0.0f;
    }
    volatile const float* xb = &xs[0][0];   // volatile: forbid b128 merging (2-way/bank = free)
    int a = py * 24 + px;
    float x0 = xb[a],      x1 = xb[a + 1],  x2 = xb[a + 2];
    float x3 = xb[a + 24], x4 = xb[a + 25], x5 = xb[a + 26];
    float x6 = xb[a + 48], x7 = xb[a + 49], x8 = xb[a + 50];
    const float* wci = conv_w + (size_t)ci * 9;   // wave-uniform -> s_load (K-cache)
#define CO_STEP(K) { const float* wp = wci + (size_t)(K) * 1152;                      \
    acc##K += x0*wp[0] + x1*wp[1] + x2*wp[2] + x3*wp[3] + x4*wp[4] + x5*wp[5]         \
            + x6*wp[6] + x7*wp[7] + x8*wp[8]; }
    CO_STEP(0)  CO_STEP(1)  CO_STEP(2)  CO_STEP(3)
    CO_STEP(4)  CO_STEP(5)  CO_STEP(6)  CO_STEP(7)
    CO_STEP(8)  CO_STEP(9)  CO_STEP(10) CO_STEP(11)
    CO_STEP(12) CO_STEP(13) CO_STEP(14) CO_STEP(15)
#undef CO_STEP
  }

  int w = tid >> 6, lane = tid & 63;
#define POOL(K) { float v = acc##K + conv_b[K]; v = v / (1.0f + expf(-v));            \
    _Pragma("unroll") for (int off = 32; off; off >>= 1) v += __shfl_down(v, off, 64);\
    if (lane == 0) redb[w][K] = v; }
  POOL(0)  POOL(1)  POOL(2)  POOL(3)
  POOL(4)  POOL(5)  POOL(6)  POOL(7)
  POOL(8)  POOL(9)  POOL(10) POOL(11)
  POOL(12) POOL(13) POOL(14) POOL(15)
#undef POOL
  __syncthreads();
  if (tid < 16) {
    g_ws[WS_POOL + bx * 16 + tid] = redb[0][tid] + redb[1][tid] + redb[2][tid] + redb[3][tid];
  }
}

// ---------- K3: all small control math (single block) ----------
__global__ __launch_bounds__(256) void k_ctrl(
    const float* __restrict__ dtp, const float* __restrict__ lin_w, const float* __restrict__ lin_b,
    const float* __restrict__ sc_w1, const float* __restrict__ sc_b1,
    const float* __restrict__ sc_w2, const float* __restrict__ sc_b2,
    const float* __restrict__ L_gen, const float* __restrict__ diss_base, const float* __restrict__ visc,
    float* __restrict__ out_dteff)
{
  __shared__ float geL[16][64];
  __shared__ float poolL[16][16];
  __shared__ float alphaL[16];
  __shared__ float hid[16][32];
  __shared__ float ctl[16][128];
  int tid = threadIdx.x;
  for (int i = tid; i < 1024; i += 256) geL[i >> 6][i & 63] = g_ws[WS_GE + i] * (1.0f / 16384.0f);
  {
    int nn = tid >> 4, co = tid & 15;
    float s = 0.0f;
    for (int tile = 0; tile < 64; ++tile) s += g_ws[WS_POOL + (nn * 64 + tile) * 16 + co];
    poolL[nn][co] = s * (1.0f / 16384.0f);
  }
  __syncthreads();
  if (tid < 16) {
    float s = lin_b[0];
    for (int co = 0; co < 16; ++co) s += poolL[tid][co] * lin_w[co];
    alphaL[tid] = 1.0f / (1.0f + expf(-s));
  }
  for (int i = tid; i < 512; i += 256) {
    int nn = i >> 5, j = i & 31;
    float s = sc_b1[j];
    for (int cc = 0; cc < 64; ++cc) s += geL[nn][cc] * sc_w1[j * 64 + cc];
    hid[nn][j] = s / (1.0f + expf(-s));
  }
  __syncthreads();
  for (int i = tid; i < 2048; i += 256) {
    int nn = i >> 7, kk = i & 127;
    int k = (kk < 64) ? kk : (kk + 64);
    float s = sc_b2[k];
    for (int j = 0; j < 32; ++j) s += hid[nn][j] * sc_w2[k * 32 + j];
    ctl[nn][kk] = tanhf(s);
  }
  __syncthreads();
  float dtv = dtp[0];
  for (int e = tid; e < 1024; e += 256) {
    int nn = e >> 6, cc = e & 63;
    float gem = geL[nn][cc];
    float dtmax = 1.0f / (10.0f * (gem + 1e-6f));
    float dte = alphaL[nn] * fminf(dtv, dtmax);
    float om = L_gen[cc] + 0.1f * ctl[nn][cc];
    float x = 0.5f * om * dte;
    float inv = 1.0f / (1.0f + x * x);
    g_ws[WS_DTEFF + e] = dte;
    g_ws[WS_ROTRE + e] = (1.0f - x * x) * inv;
    g_ws[WS_ROTIM + e] = 2.0f * x * inv;
    float vv = ctl[nn][64 + cc];
    g_ws[WS_BV + e] = 2.0f / (1.0f + expf(-vv));
    out_dteff[e] = dte;
  }
  if (tid < 64) g_ws[WS_GB + tid] = -log1pf(expf(diss_base[tid]));
  if (tid == 0) g_ws[WS_NU] = log1pf(expf(visc[0]));
}

// ---------- K4: column FFTs (bf16 panel in) + Bv/128 + REAL-PART f32 u-write ----------
__global__ __launch_bounds__(256) void k_colfft2(
    const ushort2* __restrict__ panel, float* __restrict__ outU, int ubbase)
{
  __shared__ __align__(16) float2 M2[32][132];
  __shared__ float fs[64];
  int bx = blockIdx.x;                      // b*520 + t*65 + wf
  int b = bx / 520;
  int rem = bx - b * 520;
  int t = rem / 65;
  int wf = rem - t * 65;
  int ub = ubbase + b;
  int tid = threadIdx.x, w = tid >> 6, lane = tid & 63;
  Tw tw; tw_init(lane, tw);
  int k0 = (int)(__brev((unsigned)lane) >> 25);
  const ushort2* src = panel + (((size_t)(b * 8 + t)) * 65 + wf) * 8192;
  if (tid < 64) fs[tid] = g_ws[WS_BV + b * 512 + t * 64 + tid] * (1.0f / 128.0f);
  size_t ob = ((((size_t)ub * 128) * 65 + (size_t)wf) * 8 + (size_t)t) * 64;
  for (int q = 0; q < 2; ++q) {
    __syncthreads();
    for (int i = tid; i < 2048; i += 256) {   // 2 complex per unit (bf16)
      ushort4 raw = *(const ushort4*)&src[(size_t)q * 4096 + (size_t)i * 2];
      int f = i * 2;
      int cl = f >> 7, hh = f & 127;
      *(float4*)&M2[cl][hh] = make_float4(bf2f(raw.x), bf2f(raw.y), bf2f(raw.z), bf2f(raw.w));
    }
    __syncthreads();
    for (int i = 0; i < 8; ++i) {
      int cl = w * 8 + i;
      float2 e0 = M2[cl][lane];
      float2 e1 = M2[cl][lane + 64];
      fft128(lane, e0, e1, tw);
      *(float4*)&M2[cl][k0] = make_float4(e0.x, e0.y, e1.x, e1.y);
    }
    __syncthreads();
    for (int idx = tid; idx < 2048; idx += 256) {
      int h = idx >> 4, cl2 = (idx & 15) * 2;
      int cc = q * 32 + cl2;
      float re0 = M2[cl2][h].x;
      float re1 = M2[cl2 + 1][h].x;
      float2 o = make_float2(re0 * fs[cc], re1 * fs[cc + 1]);
      *(float2*)&outU[ob + (size_t)h * 33280 + cc] = o;
    }
  }
}

// ---------- K5: A writer, REAL PART f32 at [S, 2S) ----------
__global__ __launch_bounds__(256) void k_awrite(float* __restrict__ outA)
{
  int bx = blockIdx.x;
  int h = bx / 65;
  int wf = bx - h * 65;
  float kxv = (float)wf * (1.0f / 128.0f);
  float kyf = (h < 64) ? (float)h : (float)(h - 128);
  float kyv = kyf * (1.0f / 128.0f);
  float ksq = kxv * kxv + kyv * kyv;
  float nu = g_ws[WS_NU];
  int tid = threadIdx.x;
  for (int e2 = tid; e2 < 512; e2 += 256) {
    int b = e2 >> 8, t = (e2 >> 5) & 7, cc = (e2 & 31) * 2;
    int e = b * 512 + t * 64 + cc;
    float gk0 = g_ws[WS_GB + cc] - nu * ksq;
    float gk1 = g_ws[WS_GB + cc + 1] - nu * ksq;
    float ad0 = expf(gk0 * g_ws[WS_DTEFF + e]);
    float ad1 = expf(gk1 * g_ws[WS_DTEFF + e + 1]);
    float2 vre = make_float2(ad0 * g_ws[WS_ROTRE + e], ad1 * g_ws[WS_ROTRE + e + 1]);
    size_t o1 = ((((size_t)(b * 128 + h)) * 65 + wf) * 8 + t) * 64 + cc;
    size_t o2 = o1 + 8519680ull;
    *(float2*)&outA[o1] = vre;
    *(float2*)&outA[o2] = vre;
  }
}

extern "C" void kernel_launch(void* const* d_in, const int* in_sizes, int n_in,
                              void* d_out, int out_size, void* d_ws, size_t ws_size,
                              hipStream_t stream)
{
  (void)in_sizes; (void)n_in; (void)d_ws; (void)ws_size;
  const float* zr     = (const float*)d_in[0];
  const float* zi     = (const float*)d_in[1];
  const float* dtp    = (const float*)d_in[2];
  const float* conv_w = (const float*)d_in[3];
  const float* conv_b = (const float*)d_in[4];
  const float* lin_w  = (const float*)d_in[5];
  const float* lin_b  = (const float*)d_in[6];
  const float* sc_w1  = (const float*)d_in[7];
  const float* sc_b1  = (const float*)d_in[8];
  const float* sc_w2  = (const float*)d_in[9];
  const float* sc_b2  = (const float*)d_in[10];
  const float* L_gen  = (const float*)d_in[11];
  const float* diss   = (const float*)d_in[12];
  const float* visc   = (const float*)d_in[13];

  float* out = (float*)d_out;
  size_t S = ((size_t)out_size - 1024) / 2;     // 17,039,360
  float* dt_out = out + (size_t)out_size - 1024;
  ushort2* panelR = (ushort2*)(out + S);        // bf16 panels fill A-region exactly
  ushort2* panelI = panelR + 8519680ull;

  k_rowfftP<<<1024, 256, 0, stream>>>(zr, zi, panelR, panelI);  // both row-FFT sets + |z|
  k_conv1  <<<1024, 256, 0, stream>>>(zr, zi, conv_w, conv_b);
  k_ctrl   <<<1, 256, 0, stream>>>(dtp, lin_w, lin_b, sc_w1, sc_b1, sc_w2, sc_b2, L_gen, diss, visc, dt_out);
  k_colfft2<<<1040, 256, 0, stream>>>(panelR, out, 0);          // Re(u) for ub = 0,1
  k_colfft2<<<1040, 256, 0, stream>>>(panelI, out, 2);          // Re(u) for ub = 2,3
  k_awrite <<<8320, 256, 0, stream>>>(out + S);
}